// Round 6
// baseline (136.928 us; speedup 1.0000x reference)
//
#include <hip/hip_runtime.h>
#include <hip/hip_bf16.h>
#include <math.h>

// ---- problem constants ----
#define BATCH 16
#define CIN   128
#define COUT  128
#define SS    3136          // 56*56
#define XT_ROW 8192         // shorts per padded row: 64 pcol * 128 ci
#define XT_PER_B (58*XT_ROW)
#define NKB   18

typedef __attribute__((ext_vector_type(8))) __bf16 bf16x8;
typedef __attribute__((ext_vector_type(4))) float  floatx4;

static __device__ __forceinline__ unsigned short f2bf(float f) {
  union { float f; unsigned u; } v; v.f = f;
  unsigned r = v.u + 0x7fffu + ((v.u >> 16) & 1u);   // RNE
  return (unsigned short)(r >> 16);
}
static __device__ __forceinline__ float bf2f(unsigned short u) {
  union { unsigned u; float f; } v; v.u = ((unsigned)u) << 16; return v.f;
}

static __device__ __forceinline__ float waveReduceSum(float v) {
  #pragma unroll
  for (int off = 32; off > 0; off >>= 1) v += __shfl_xor(v, off, 64);
  return v;
}

static __device__ __forceinline__ void load_lds16(const void* g, void* l) {
  __builtin_amdgcn_global_load_lds(
      (const __attribute__((address_space(1))) void*)g,
      (__attribute__((address_space(3))) void*)l, 16, 0, 0);
}

// K0: fused pad+transpose to NHWC bf16 + attention mask row + exp + per-row
// context partials. No softmax max-subtraction (mask is O(1), shift-invariant).
__global__ void k0_padT(const float* __restrict__ x, const float* __restrict__ w_mask,
                        const float* __restrict__ b_mask,
                        unsigned short* __restrict__ xT, float* __restrict__ rowsum,
                        float* __restrict__ pctx) {
  int b = blockIdx.y, prow = blockIdx.x, t = threadIdx.x;
  int y = prow - 1;
  __shared__ unsigned short sx[128 * 58];   // row stride 58 (odd word-stride -> spread banks)
  __shared__ float swm[128];
  __shared__ float red[4 * 56];
  __shared__ float se[56];
  bool rowvalid = ((unsigned)y < 56u);
  if (t < 128) swm[t] = w_mask[t];
  if (rowvalid) {
    int ci = t >> 1, h = t & 1;
    const float4* src = (const float4*)(x + (size_t)(b * 128 + ci) * SS + y * 56 + h * 28);
    #pragma unroll
    for (int c4 = 0; c4 < 7; c4++) {
      float4 v = src[c4];
      int base = ci * 58 + h * 28 + c4 * 4;
      sx[base]     = f2bf(v.x);
      sx[base + 1] = f2bf(v.y);
      sx[base + 2] = f2bf(v.z);
      sx[base + 3] = f2bf(v.w);
    }
  } else {
    for (int i = t; i < 128 * 58; i += 256) sx[i] = 0;
  }
  __syncthreads();
  if (rowvalid && t < 224) {
    int xx = t % 56, g = t / 56;
    float acc = 0.f;
    #pragma unroll
    for (int k = 0; k < 32; k++) {
      int ci = g * 32 + k;
      acc += bf2f(sx[ci * 58 + xx]) * swm[ci];
    }
    red[g * 56 + xx] = acc;
  }
  __syncthreads();
  float e = 0.f;
  if (rowvalid && t < 56) {
    float m = red[t] + red[56 + t] + red[112 + t] + red[168 + t] + b_mask[0];
    e = expf(m);
    se[t] = e;
  }
  if (t < 64) {
    float s = waveReduceSum(e);
    if (t == 0) rowsum[b * 58 + prow] = s;   // 0 on pad rows
  }
  __syncthreads();   // se ready
  {
    int c = t >> 1, h = t & 1;
    float acc = 0.f;
    if (rowvalid) {
      #pragma unroll
      for (int j = 0; j < 28; j++)
        acc += bf2f(sx[c * 58 + h * 28 + j]) * se[h * 28 + j];
    }
    acc += __shfl_xor(acc, 1, 64);
    if (h == 0) pctx[(size_t)(b * 58 + prow) * 128 + c] = acc;  // 0 on pad rows
  }
  // NHWC write: thread t -> pcol = t>>2, ci block = (t&3)*32, 64B contiguous
  int pcol = t >> 2, cig = t & 3;
  int xx = pcol - 1;
  bool colv = rowvalid && ((unsigned)xx < 56u);
  unsigned short tmp[32];
  #pragma unroll
  for (int i = 0; i < 32; i++)
    tmp[i] = colv ? sx[(cig * 32 + i) * 58 + xx] : (unsigned short)0;
  unsigned short* dst = xT + ((size_t)(b * 58 + prow) * 64 + pcol) * 128 + cig * 32;
  #pragma unroll
  for (int q = 0; q < 4; q++)
    *reinterpret_cast<uint4*>(dst + q * 8) = *reinterpret_cast<const uint4*>(tmp + q * 8);
}

// K5: fused ctx-reduction + bottleneck MLP + per-sample weight generation.
// grid (co=128, b=16), 128 threads. wd[b][co][kb][kq(swizzled)].
__global__ void k5_gen(const float* __restrict__ rowsum, const float* __restrict__ pctx,
                       const float* __restrict__ w1, const float* __restrict__ b1,
                       const float* __restrict__ ln_g, const float* __restrict__ ln_b,
                       const float* __restrict__ w2, const float* __restrict__ b2,
                       const float* __restrict__ w_fc, const float* __restrict__ b_fc,
                       unsigned short* __restrict__ wd) {
  int co = blockIdx.x, b = blockIdx.y, t = threadIdx.x;
  __shared__ float sc[128], st[16], sn[16], sa[2], shz;
  float rv = (t < 58) ? rowsum[b * 58 + t] : 0.f;
  float acc = 0.f;
  #pragma unroll
  for (int r = 0; r < 58; r++) acc += pctx[(size_t)(b * 58 + r) * 128 + t];
  if (t < 64) {
    float z = waveReduceSum(rv);
    if (t == 0) shz = 1.0f / z;
  }
  __syncthreads();
  sc[t] = acc * shz;
  __syncthreads();
  if (t < 16) {
    float s = b1[t];
    #pragma unroll 8
    for (int c = 0; c < 128; c++) s += sc[c] * w1[t * 128 + c];
    st[t] = s;
  }
  __syncthreads();
  float mu = 0.f, m2 = 0.f;
  #pragma unroll
  for (int r = 0; r < 16; r++) { float v = st[r]; mu += v; m2 += v * v; }
  mu *= (1.f / 16.f); m2 *= (1.f / 16.f);
  float rstd = rsqrtf(m2 - mu * mu + 1e-5f);
  if (t < 16) {
    float v = (st[t] - mu) * rstd * ln_g[t] + ln_b[t];
    sn[t] = fmaxf(v, 0.f);
  }
  __syncthreads();
  if (t < 2) {
    int mo = 2 * co + t;
    float s = b2[mo];
    #pragma unroll
    for (int r = 0; r < 16; r++) s += sn[r] * w2[mo * 16 + r];
    sa[t] = 1.f / (1.f + expf(-s));
  }
  __syncthreads();
  float a0 = sa[0], a1 = sa[1];
  const float* wrow = w_fc + co * 1152;
  const float* brow = b_fc + co * 1152;
  unsigned short* drow = wd + (size_t)(b * 128 + co) * 1152;
  #pragma unroll
  for (int r = 0; r < 9; r++) {
    int e = t + 128 * r;
    int ci = e / 9, khw = e - (e / 9) * 9;
    float v = (ci < 64 ? a0 : a1) * wrow[e] + brow[e];
    int kb = khw * 2 + (ci >> 6);
    int kq = ci & 63;
    int pos = (((kq >> 3) ^ (co & 7)) << 3) | (kq & 7);
    drow[kb * 64 + pos] = f2bf(v);
  }
}

// K6: implicit-GEMM conv, 512 threads, tile 128co x 128s (2 out rows).
// B-RESIDENT: the 4 halo'd NHWC input rows (64 KB) are DMA-staged into LDS once
// (chunk-XOR swizzle via source permutation); each K-step's (kh,kw) shift is
// applied at LDS fragment-read time. Only the 16 KB A panel is staged per step.
// LDS = 80 KB -> 2 blocks/CU.
__global__ __launch_bounds__(512, 4) void k6_conv(const unsigned short* __restrict__ xT,
                                                  const unsigned short* __restrict__ wd,
                                                  float* __restrict__ out) {
  __shared__ __align__(16) unsigned short As[8192];    // 16 KB [co128][kq64] (pre-swizzled)
  __shared__ __align__(16) unsigned short Bs[32768];   // 64 KB [row4][pcol64][ci-chunk16][8]
  int t = threadIdx.x;
  int b = blockIdx.y, y0 = blockIdx.x * 2;
  int wave = t >> 6, lane = t & 63, l15 = lane & 15, quad = lane >> 4;
  int x7 = lane & 7;
  const unsigned short* wp  = wd + (size_t)b * (128 * 1152);
  const unsigned short* xTb = xT + (size_t)b * XT_PER_B + (size_t)y0 * XT_ROW;  // prow0 = y0

  // ---- stage B once: 4096 16B-chunks, 8 DMA/thread, source-permuted swizzle ----
  #pragma unroll
  for (int i = 0; i < 8; i++) {
    int g = i * 512 + t;                 // t == wave*64 + lane
    int row  = g >> 10;
    int pcol = (g >> 4) & 63;
    int c    = g & 15;
    int csrc = (c & 8) | ((c & 7) ^ (pcol & 7));
    load_lds16(xTb + (size_t)((row * 64 + pcol) * 16 + csrc) * 8,
               &Bs[(size_t)(i * 512 + wave * 64) * 8]);
  }

  // A staging: 1024 chunks/step, 2 per thread (ch0 = t, ch1 = t + 512)
  int offA0 = (t >> 3) * 1152 + (t & 7) * 8;
  int ch1 = t + 512;
  int offA1 = (ch1 >> 3) * 1152 + (ch1 & 7) * 8;

  int s_base = (wave & 3) * 32;
  int co_b   = (wave >> 2) * 64;

  // per-lane B row/col for the 2 s-fragments (pad lanes s>=112 clamp into row 0)
  int srw[2], scl[2];
  #pragma unroll
  for (int j = 0; j < 2; j++) {
    int s = s_base + j * 16 + l15;
    int r = (s >= 56) ? 1 : 0;
    int cc = s - r * 56;
    if (s >= 112) { r = 0; cc = s - 112; }
    srw[j] = r; scl[j] = cc;
  }

  floatx4 acc[4][2];
  floatx4 zero = {0.f, 0.f, 0.f, 0.f};
  #pragma unroll
  for (int i = 0; i < 4; i++)
    #pragma unroll
    for (int j = 0; j < 2; j++) acc[i][j] = zero;

  #pragma unroll 1
  for (int kb = 0; kb < NKB; kb++) {
    int khw = kb >> 1;
    int kh = khw / 3;
    int kw = khw - kh * 3;
    __syncthreads();                      // prior step's A-frag reads complete
    load_lds16(wp + offA0 + kb * 64, &As[wave * 512]);
    load_lds16(wp + offA1 + kb * 64, &As[4096 + wave * 512]);
    __syncthreads();                      // all DMA drained (incl. B on kb=0)
    #pragma unroll
    for (int kk = 0; kk < 2; kk++) {
      bf16x8 af[4], bfr[2];
      int pcA = ((kk * 4 + quad) ^ x7) << 3;
      #pragma unroll
      for (int i = 0; i < 4; i++)
        af[i] = *reinterpret_cast<const bf16x8*>(&As[(co_b + i * 16 + l15) * 64 + pcA]);
      int c = ((kb & 1) << 3) + kk * 4 + quad;
      #pragma unroll
      for (int j = 0; j < 2; j++) {
        int pq = scl[j] + kw;
        int cs = (c & 8) | ((c & 7) ^ (pq & 7));
        bfr[j] = *reinterpret_cast<const bf16x8*>(&Bs[(((srw[j] + kh) * 64 + pq) * 16 + cs) * 8]);
      }
      #pragma unroll
      for (int i = 0; i < 4; i++)
        #pragma unroll
        for (int j = 0; j < 2; j++)
          acc[i][j] = __builtin_amdgcn_mfma_f32_16x16x32_bf16(af[i], bfr[j], acc[i][j], 0, 0, 0);
    }
  }

  // epilogue: D col (l15) -> s, row (quad*4+r) -> co
  float* ob = out + (size_t)b * COUT * SS + y0 * 56;
  #pragma unroll
  for (int i = 0; i < 4; i++) {
    #pragma unroll
    for (int j = 0; j < 2; j++) {
      int sl = s_base + j * 16 + l15;
      if (sl < 112) {
        int row = (sl >= 56) ? 1 : 0;
        int col = sl - row * 56;
        #pragma unroll
        for (int r = 0; r < 4; r++) {
          int co = co_b + i * 16 + quad * 4 + r;
          ob[(size_t)co * SS + row * 56 + col] = acc[i][j][r];
        }
      }
    }
  }
}

extern "C" void kernel_launch(void* const* d_in, const int* in_sizes, int n_in,
                              void* d_out, int out_size, void* d_ws, size_t ws_size,
                              hipStream_t stream) {
  const float* x      = (const float*)d_in[0];
  const float* w_mask = (const float*)d_in[1];
  const float* b_mask = (const float*)d_in[2];
  const float* w1     = (const float*)d_in[3];
  const float* b1     = (const float*)d_in[4];
  const float* ln_g   = (const float*)d_in[5];
  const float* ln_b   = (const float*)d_in[6];
  const float* w2     = (const float*)d_in[7];
  const float* b2     = (const float*)d_in[8];
  const float* w_fc   = (const float*)d_in[9];
  const float* b_fc   = (const float*)d_in[10];
  float* out = (float*)d_out;

  char* ws = (char*)d_ws;
  unsigned short* xT  = (unsigned short*)(ws);               // 15,204,352 B
  unsigned short* wdw = (unsigned short*)(ws + 15204352);    //  4,718,592 B
  float* rowsum = (float*)(ws + 19922944);                   //      3,712 B
  float* pctx   = (float*)(ws + 19927040);                   //    475,136 B

  k0_padT<<<dim3(58, 16),  dim3(256), 0, stream>>>(x, w_mask, b_mask, xT, rowsum, pctx);
  k5_gen <<<dim3(128, 16), dim3(128), 0, stream>>>(rowsum, pctx, w1, b1, ln_g, ln_b,
                                                   w2, b2, w_fc, b_fc, wdw);
  k6_conv<<<dim3(28, 16),  dim3(512), 0, stream>>>(xT, wdw, out);
}

// Round 7
// 136.132 us; speedup vs baseline: 1.0059x; 1.0059x over previous
//
#include <hip/hip_runtime.h>
#include <hip/hip_bf16.h>
#include <math.h>

// ---- problem constants ----
#define BATCH 16
#define CIN   128
#define COUT  128
#define SS    3136          // 56*56
#define XT_ROW 8192         // shorts per padded row: 64 pcol * 128 ci
#define XT_PER_B (58*XT_ROW)

typedef __attribute__((ext_vector_type(8))) __bf16 bf16x8;
typedef __attribute__((ext_vector_type(4))) float  floatx4;

static __device__ __forceinline__ unsigned short f2bf(float f) {
  union { float f; unsigned u; } v; v.f = f;
  unsigned r = v.u + 0x7fffu + ((v.u >> 16) & 1u);   // RNE
  return (unsigned short)(r >> 16);
}
static __device__ __forceinline__ float bf2f(unsigned short u) {
  union { unsigned u; float f; } v; v.u = ((unsigned)u) << 16; return v.f;
}

static __device__ __forceinline__ float waveReduceSum(float v) {
  #pragma unroll
  for (int off = 32; off > 0; off >>= 1) v += __shfl_xor(v, off, 64);
  return v;
}

static __device__ __forceinline__ void load_lds16(const void* g, void* l) {
  __builtin_amdgcn_global_load_lds(
      (const __attribute__((address_space(1))) void*)g,
      (__attribute__((address_space(3))) void*)l, 16, 0, 0);
}

#define ASM_WAIT_VM2 asm volatile("s_waitcnt vmcnt(2)" ::: "memory")
#define ASM_WAIT_VM0 asm volatile("s_waitcnt vmcnt(0)" ::: "memory")
#define BARRIER      __builtin_amdgcn_s_barrier()

// K0: fused pad+transpose to NHWC bf16 + attention mask row + exp + per-row
// context partials. No softmax max-subtraction (mask is O(1), shift-invariant).
__global__ void k0_padT(const float* __restrict__ x, const float* __restrict__ w_mask,
                        const float* __restrict__ b_mask,
                        unsigned short* __restrict__ xT, float* __restrict__ rowsum,
                        float* __restrict__ pctx) {
  int b = blockIdx.y, prow = blockIdx.x, t = threadIdx.x;
  int y = prow - 1;
  __shared__ unsigned short sx[128 * 58];   // row stride 58 (odd word-stride -> spread banks)
  __shared__ float swm[128];
  __shared__ float red[4 * 56];
  __shared__ float se[56];
  bool rowvalid = ((unsigned)y < 56u);
  if (t < 128) swm[t] = w_mask[t];
  if (rowvalid) {
    int ci = t >> 1, h = t & 1;
    const float4* src = (const float4*)(x + (size_t)(b * 128 + ci) * SS + y * 56 + h * 28);
    #pragma unroll
    for (int c4 = 0; c4 < 7; c4++) {
      float4 v = src[c4];
      int base = ci * 58 + h * 28 + c4 * 4;
      sx[base]     = f2bf(v.x);
      sx[base + 1] = f2bf(v.y);
      sx[base + 2] = f2bf(v.z);
      sx[base + 3] = f2bf(v.w);
    }
  } else {
    for (int i = t; i < 128 * 58; i += 256) sx[i] = 0;
  }
  __syncthreads();
  if (rowvalid && t < 224) {
    int xx = t % 56, g = t / 56;
    float acc = 0.f;
    #pragma unroll
    for (int k = 0; k < 32; k++) {
      int ci = g * 32 + k;
      acc += bf2f(sx[ci * 58 + xx]) * swm[ci];
    }
    red[g * 56 + xx] = acc;
  }
  __syncthreads();
  float e = 0.f;
  if (rowvalid && t < 56) {
    float m = red[t] + red[56 + t] + red[112 + t] + red[168 + t] + b_mask[0];
    e = expf(m);
    se[t] = e;
  }
  if (t < 64) {
    float s = waveReduceSum(e);
    if (t == 0) rowsum[b * 58 + prow] = s;   // 0 on pad rows
  }
  __syncthreads();   // se ready
  {
    int c = t >> 1, h = t & 1;
    float acc = 0.f;
    if (rowvalid) {
      #pragma unroll
      for (int j = 0; j < 28; j++)
        acc += bf2f(sx[c * 58 + h * 28 + j]) * se[h * 28 + j];
    }
    acc += __shfl_xor(acc, 1, 64);
    if (h == 0) pctx[(size_t)(b * 58 + prow) * 128 + c] = acc;  // 0 on pad rows
  }
  // NHWC write: thread t -> pcol = t>>2, ci block = (t&3)*32, 64B contiguous
  int pcol = t >> 2, cig = t & 3;
  int xx = pcol - 1;
  bool colv = rowvalid && ((unsigned)xx < 56u);
  unsigned short tmp[32];
  #pragma unroll
  for (int i = 0; i < 32; i++)
    tmp[i] = colv ? sx[(cig * 32 + i) * 58 + xx] : (unsigned short)0;
  unsigned short* dst = xT + ((size_t)(b * 58 + prow) * 64 + pcol) * 128 + cig * 32;
  #pragma unroll
  for (int q = 0; q < 4; q++)
    *reinterpret_cast<uint4*>(dst + q * 8) = *reinterpret_cast<const uint4*>(tmp + q * 8);
}

// K5: fused ctx-reduction + bottleneck MLP + per-sample weight generation.
// grid (co=128, b=16), 128 threads. wd[b][co][kb][kq(swizzled)].
// K-step order is ci-half-major: kb = (ci>>6)*9 + (kh*3+kw).
__global__ void k5_gen(const float* __restrict__ rowsum, const float* __restrict__ pctx,
                       const float* __restrict__ w1, const float* __restrict__ b1,
                       const float* __restrict__ ln_g, const float* __restrict__ ln_b,
                       const float* __restrict__ w2, const float* __restrict__ b2,
                       const float* __restrict__ w_fc, const float* __restrict__ b_fc,
                       unsigned short* __restrict__ wd) {
  int co = blockIdx.x, b = blockIdx.y, t = threadIdx.x;
  __shared__ float sc[128], st[16], sn[16], sa[2], shz;
  float rv = (t < 58) ? rowsum[b * 58 + t] : 0.f;
  float acc = 0.f;
  #pragma unroll
  for (int r = 0; r < 58; r++) acc += pctx[(size_t)(b * 58 + r) * 128 + t];
  if (t < 64) {
    float z = waveReduceSum(rv);
    if (t == 0) shz = 1.0f / z;
  }
  __syncthreads();
  sc[t] = acc * shz;
  __syncthreads();
  if (t < 16) {
    float s = b1[t];
    #pragma unroll 8
    for (int c = 0; c < 128; c++) s += sc[c] * w1[t * 128 + c];
    st[t] = s;
  }
  __syncthreads();
  float mu = 0.f, m2 = 0.f;
  #pragma unroll
  for (int r = 0; r < 16; r++) { float v = st[r]; mu += v; m2 += v * v; }
  mu *= (1.f / 16.f); m2 *= (1.f / 16.f);
  float rstd = rsqrtf(m2 - mu * mu + 1e-5f);
  if (t < 16) {
    float v = (st[t] - mu) * rstd * ln_g[t] + ln_b[t];
    sn[t] = fmaxf(v, 0.f);
  }
  __syncthreads();
  if (t < 2) {
    int mo = 2 * co + t;
    float s = b2[mo];
    #pragma unroll
    for (int r = 0; r < 16; r++) s += sn[r] * w2[mo * 16 + r];
    sa[t] = 1.f / (1.f + expf(-s));
  }
  __syncthreads();
  float a0 = sa[0], a1 = sa[1];
  const float* wrow = w_fc + co * 1152;
  const float* brow = b_fc + co * 1152;
  unsigned short* drow = wd + (size_t)(b * 128 + co) * 1152;
  #pragma unroll
  for (int r = 0; r < 9; r++) {
    int e = t + 128 * r;
    int ci = e / 9, khw = e - (e / 9) * 9;
    float v = (ci < 64 ? a0 : a1) * wrow[e] + brow[e];
    int kb = (ci >> 6) * 9 + khw;
    int kq = ci & 63;
    int pos = (((kq >> 3) ^ (co & 7)) << 3) | (kq & 7);
    drow[kb * 64 + pos] = f2bf(v);
  }
}

// K6: implicit-GEMM conv, 512 threads, tile 128co x 128s (2 out rows).
// Two ci-half phases: B for the phase (4 halo'd rows x 58 pcol x 64 ci = 29 KB)
// staged once; A (16 KB panels) DOUBLE-BUFFERED with raw s_barrier +
// s_waitcnt vmcnt(2) so step k+1's DMA stays in flight under step k's MFMA.
// LDS = 61 KB -> 2 blocks/CU (VGPR kept slim for 4 waves/EU residency).
__global__ __launch_bounds__(512, 4) void k6_conv(const unsigned short* __restrict__ xT,
                                                  const unsigned short* __restrict__ wd,
                                                  float* __restrict__ out) {
  __shared__ __align__(16) unsigned short As[2][8192];   // 2 x 16 KB [co128][kq64] (pre-swizzled)
  __shared__ __align__(16) unsigned short Bs[14848];     // 29 KB [row4][pcol58][c8][8]
  int t = threadIdx.x;
  int b = blockIdx.y, y0 = blockIdx.x * 2;
  int wave = t >> 6, lane = t & 63, l15 = lane & 15, quad = lane >> 4;
  int x7 = lane & 7;
  const unsigned short* wp  = wd + (size_t)b * (128 * 1152);
  const unsigned short* xTb = xT + (size_t)b * XT_PER_B + (size_t)y0 * XT_ROW;  // prow0 = y0

  // A staging: 1024 chunks/panel, 2 per thread (ch0 = t, ch1 = t + 512)
  int offA0 = (t >> 3) * 1152 + (t & 7) * 8;
  int ch1 = t + 512;
  int offA1 = (ch1 >> 3) * 1152 + (ch1 & 7) * 8;

  int s_base = (wave & 3) * 32;
  int co_b   = (wave >> 2) * 64;

  // per-lane B row/col for the 2 s-fragments (pad lanes s>=112 clamp into row 0)
  int srw[2], scl[2];
  #pragma unroll
  for (int j = 0; j < 2; j++) {
    int s = s_base + j * 16 + l15;
    int r = (s >= 56) ? 1 : 0;
    int cc = s - r * 56;
    if (s >= 112) { r = 0; cc = s - 112; }
    srw[j] = r; scl[j] = cc;
  }

  floatx4 acc[4][2];
  floatx4 zero = {0.f, 0.f, 0.f, 0.f};
  #pragma unroll
  for (int i = 0; i < 4; i++)
    #pragma unroll
    for (int j = 0; j < 2; j++) acc[i][j] = zero;

  #pragma unroll 1
  for (int p = 0; p < 2; p++) {
    // ---- stage B half (1856 chunks = 29 wave-chunks of 64), source-permuted swizzle ----
    #pragma unroll
    for (int r = 0; r < 4; r++) {
      int wc = r * 8 + wave;
      if (wc < 29) {
        int g = wc * 64 + lane;
        int row = g / 464;
        int rem = g - row * 464;
        int pcol = rem >> 3, c = rem & 7;
        int csrc = c ^ (pcol & 7);
        load_lds16(xTb + (size_t)(row * 64 + pcol) * 128 + p * 64 + csrc * 8,
                   &Bs[wc * 512]);
      }
    }
    // ---- prime A pipeline ----
    load_lds16(wp + offA0 + (p * 9) * 64, &As[0][wave * 512]);
    load_lds16(wp + offA1 + (p * 9) * 64, &As[0][4096 + wave * 512]);
    #pragma unroll 1
    for (int k = 0; k < 9; k++) {
      int P = k & 1;
      if (k < 8) {
        load_lds16(wp + offA0 + (p * 9 + k + 1) * 64, &As[1 - P][wave * 512]);
        load_lds16(wp + offA1 + (p * 9 + k + 1) * 64, &As[1 - P][4096 + wave * 512]);
        ASM_WAIT_VM2;   // own step-k DMAs (and B on k=0) done; k+1's float
      } else {
        ASM_WAIT_VM0;
      }
      BARRIER;          // all waves' step-k data resident
      int kh = k / 3, kw = k - kh * 3;
      #pragma unroll
      for (int kk = 0; kk < 2; kk++) {
        bf16x8 af[4], bfr[2];
        int pcA = ((kk * 4 + quad) ^ x7) << 3;
        #pragma unroll
        for (int i = 0; i < 4; i++)
          af[i] = *reinterpret_cast<const bf16x8*>(&As[P][(co_b + i * 16 + l15) * 64 + pcA]);
        int c = kk * 4 + quad;
        #pragma unroll
        for (int j = 0; j < 2; j++) {
          int pq = scl[j] + kw;
          bfr[j] = *reinterpret_cast<const bf16x8*>(
              &Bs[(((srw[j] + kh) * 58 + pq) * 8 + (c ^ (pq & 7))) * 8]);
        }
        #pragma unroll
        for (int i = 0; i < 4; i++)
          #pragma unroll
          for (int j = 0; j < 2; j++)
            acc[i][j] = __builtin_amdgcn_mfma_f32_16x16x32_bf16(af[i], bfr[j], acc[i][j], 0, 0, 0);
      }
      BARRIER;          // all waves done reading buf P before it is re-targeted
    }
  }

  // epilogue: D col (l15) -> s, row (quad*4+r) -> co
  float* ob = out + (size_t)b * COUT * SS + y0 * 56;
  #pragma unroll
  for (int i = 0; i < 4; i++) {
    #pragma unroll
    for (int j = 0; j < 2; j++) {
      int sl = s_base + j * 16 + l15;
      if (sl < 112) {
        int row = (sl >= 56) ? 1 : 0;
        int col = sl - row * 56;
        #pragma unroll
        for (int r = 0; r < 4; r++) {
          int co = co_b + i * 16 + quad * 4 + r;
          ob[(size_t)co * SS + row * 56 + col] = acc[i][j][r];
        }
      }
    }
  }
}

extern "C" void kernel_launch(void* const* d_in, const int* in_sizes, int n_in,
                              void* d_out, int out_size, void* d_ws, size_t ws_size,
                              hipStream_t stream) {
  const float* x      = (const float*)d_in[0];
  const float* w_mask = (const float*)d_in[1];
  const float* b_mask = (const float*)d_in[2];
  const float* w1     = (const float*)d_in[3];
  const float* b1     = (const float*)d_in[4];
  const float* ln_g   = (const float*)d_in[5];
  const float* ln_b   = (const float*)d_in[6];
  const float* w2     = (const float*)d_in[7];
  const float* b2     = (const float*)d_in[8];
  const float* w_fc   = (const float*)d_in[9];
  const float* b_fc   = (const float*)d_in[10];
  float* out = (float*)d_out;

  char* ws = (char*)d_ws;
  unsigned short* xT  = (unsigned short*)(ws);               // 15,204,352 B
  unsigned short* wdw = (unsigned short*)(ws + 15204352);    //  4,718,592 B
  float* rowsum = (float*)(ws + 19922944);                   //      3,712 B
  float* pctx   = (float*)(ws + 19927040);                   //    475,136 B

  k0_padT<<<dim3(58, 16),  dim3(256), 0, stream>>>(x, w_mask, b_mask, xT, rowsum, pctx);
  k5_gen <<<dim3(128, 16), dim3(128), 0, stream>>>(rowsum, pctx, w1, b1, ln_g, ln_b,
                                                   w2, b2, w_fc, b_fc, wdw);
  k6_conv<<<dim3(28, 16),  dim3(512), 0, stream>>>(xT, wdw, out);
}